// Round 7
// baseline (149.665 us; speedup 1.0000x reference)
//
#include <hip/hip_runtime.h>
#include <stdint.h>

#define TB 256

typedef __bf16 bf16x8 __attribute__((ext_vector_type(8)));
typedef float f32x4 __attribute__((ext_vector_type(4)));

#define AS1 __attribute__((address_space(1)))
#define AS3 __attribute__((address_space(3)))
// direct global->LDS, 16B per lane; LDS dest = wave-uniform base + lane*16
#define GLOAD16(gp, lp) __builtin_amdgcn_global_load_lds( \
    (const AS1 unsigned int*)(gp), (AS3 unsigned int*)(lp), 16, 0, 0)

__device__ __forceinline__ unsigned short f2bf(float f) {
  uint32_t u = __builtin_bit_cast(uint32_t, f);
  u += 0x7fffu + ((u >> 16) & 1u);
  return (unsigned short)(u >> 16);
}

// counted-vmcnt barriers (T4); sched_barrier(0) fences per rule #18
__device__ __forceinline__ void waitbar5() {
  __builtin_amdgcn_sched_barrier(0);
  asm volatile("s_waitcnt vmcnt(5) lgkmcnt(0)" ::: "memory");
  __builtin_amdgcn_s_barrier();
  __builtin_amdgcn_sched_barrier(0);
}
__device__ __forceinline__ void waitbar3() {
  __builtin_amdgcn_sched_barrier(0);
  asm volatile("s_waitcnt vmcnt(3) lgkmcnt(0)" ::: "memory");
  __builtin_amdgcn_s_barrier();
  __builtin_amdgcn_sched_barrier(0);
}
__device__ __forceinline__ void waitbar0() {
  __builtin_amdgcn_sched_barrier(0);
  asm volatile("s_waitcnt vmcnt(0) lgkmcnt(0)" ::: "memory");
  __builtin_amdgcn_s_barrier();
  __builtin_amdgcn_sched_barrier(0);
}

// ---------------- kernel: fused prep ----------------
// [0,4096): x f32 -> bf16
// [4096,4896): W_lvl2 [25][2048][41] -> wlt bf16 [28][48][2048] (cols 41..47 = 0)
// [4896,4928): W_root [2048][26] -> wrt bf16 [32][2048] (rows 26..31 = 0)
// 4928: labels normalize + pengl=0 ; 4929..4931: zero wlt groups 25..27
__global__ __launch_bounds__(TB) void k_prep(const float* __restrict__ x,
                                             const float* __restrict__ wl,
                                             const float* __restrict__ wr,
                                             const int* __restrict__ labraw,
                                             unsigned short* __restrict__ xbf,
                                             unsigned short* __restrict__ wlt,
                                             unsigned short* __restrict__ wrt,
                                             int* __restrict__ lab32,
                                             float* __restrict__ pengl) {
  int bid = blockIdx.x, t = threadIdx.x;
  if (bid < 4096) {
    int idx = bid * TB + t;
    const float4* xin = reinterpret_cast<const float4*>(x);
    float4 a = xin[idx * 2], b = xin[idx * 2 + 1];
    uint32_t p0 = f2bf(a.x) | ((uint32_t)f2bf(a.y) << 16);
    uint32_t p1 = f2bf(a.z) | ((uint32_t)f2bf(a.w) << 16);
    uint32_t p2 = f2bf(b.x) | ((uint32_t)f2bf(b.y) << 16);
    uint32_t p3 = f2bf(b.z) | ((uint32_t)f2bf(b.w) << 16);
    reinterpret_cast<uint4*>(xbf)[idx] = make_uint4(p0, p1, p2, p3);
  } else if (bid < 4928) {
    __shared__ float ld_f[2624];
    int b2 = bid - 4096;
    if (b2 < 800) {
      int n = b2 / 32, dt = b2 % 32, d0 = dt * 64;
      const float* src = wl + ((size_t)n * 2048 + d0) * 41;
      for (int i = 0; i < 11; i++) { int lin = t + TB * i; if (lin < 2624) ld_f[lin] = src[lin]; }
      __syncthreads();
      unsigned short* dst = wlt + (size_t)n * 48 * 2048 + d0;
      for (int i = 0; i < 12; i++) {
        int lin = t + TB * i;  // 3072 = 48*64
        int wc = lin >> 6, d = lin & 63;
        float v = (wc < 41) ? ld_f[d * 41 + wc] : 0.f;
        dst[(size_t)wc * 2048 + d] = f2bf(v);
      }
    } else {
      int dt = b2 - 800, d0 = dt * 64;
      const float* src = wr + (size_t)d0 * 26;
      for (int i = 0; i < 7; i++) { int lin = t + TB * i; if (lin < 1664) ld_f[lin] = src[lin]; }
      __syncthreads();
      unsigned short* dst = wrt + d0;
      for (int i = 0; i < 8; i++) {
        int lin = t + TB * i;  // 2048 = 32*64
        int wc = lin >> 6, d = lin & 63;
        float v = (wc < 26) ? ld_f[d * 26 + wc] : 0.f;
        dst[(size_t)wc * 2048 + d] = f2bf(v);
      }
    }
  } else if (bid == 4928) {
    __shared__ int orred;
    if (t == 0) { orred = 0; pengl[0] = 0.f; }
    __syncthreads();
    int acc = 0;
    for (int i = t; i < 2048; i += TB) acc |= labraw[2 * i + 1];
    atomicOr(&orred, acc);
    __syncthreads();
    bool i64 = (orred == 0);
    for (int i = t; i < 4096; i += TB) lab32[i] = i64 ? labraw[2 * i] : labraw[i];
  } else {
    int g = 25 + (bid - 4929);
    uint4* p = reinterpret_cast<uint4*>(wlt + (size_t)g * 48 * 2048);
    uint4 z = make_uint4(0, 0, 0, 0);
    for (int i = t; i < 12288; i += TB) p[i] = z;
  }
}

// ---------------- kernel: root GEMM + softmax + ce_root ----------------
// 256 blocks x 512 threads; 16 rows/block; 8 waves split K 8-way per K-step(256)
__global__ __launch_bounds__(512) void k_root(const unsigned short* __restrict__ xbf,
                                              const unsigned short* __restrict__ wrt,
                                              const float* __restrict__ br,
                                              const int* __restrict__ labels,
                                              float* __restrict__ rootp,
                                              float* __restrict__ pengl) {
  __shared__ __align__(16) unsigned char lds3[3][24576];  // x 8K @0, w 16K @8192
  int r0 = blockIdx.x * 16;
  int tid = threadIdx.x, lane = tid & 63, wave = tid >> 6;  // wave in [0,8)
  int lq = lane >> 4, lr = lane & 15;
  const unsigned short* xg = xbf + (size_t)r0 * 2048;
  f32x4 acc[2] = {};

#define STAGE_RT(lb, kk)                                                              \
  do {                                                                                \
    { /* x: 512 chunks, 1/thread */                                                   \
      int row = tid >> 5, s = tid & 31;                                               \
      const unsigned short* gp = xg + (size_t)row * 2048 + (kk) + ((s ^ row) << 3);   \
      GLOAD16(gp, (lb) + (size_t)tid * 16);                                           \
    }                                                                                 \
    _Pragma("unroll")                                                                 \
    for (int i = 0; i < 2; i++) { /* w: 1024 chunks, 2/thread */                      \
      int idx = i * 512 + tid;                                                        \
      int wc = idx >> 5, s = idx & 31;                                                \
      const unsigned short* gp = wrt + (size_t)wc * 2048 + (kk) + ((s ^ (wc & 31)) << 3); \
      GLOAD16(gp, (lb) + 8192 + (size_t)idx * 16);                                    \
    }                                                                                 \
  } while (0)

#define COMPUTE_RT(base)                                                              \
  do {                                                                                \
    int g = (wave << 2) | lq; /* this wave's k-chunk in [0,32) */                     \
    bf16x8 af[2], bx;                                                                 \
    _Pragma("unroll")                                                                 \
    for (int mt = 0; mt < 2; mt++) {                                                  \
      int c = mt * 16 + lr;                                                           \
      af[mt] = *reinterpret_cast<const bf16x8*>((base) + 8192 + c * 512 + ((g ^ (c & 31)) << 4)); \
    }                                                                                 \
    bx = *reinterpret_cast<const bf16x8*>((base) + lr * 512 + ((g ^ lr) << 4));       \
    _Pragma("unroll")                                                                 \
    for (int mt = 0; mt < 2; mt++)                                                    \
      acc[mt] = __builtin_amdgcn_mfma_f32_16x16x32_bf16(af[mt], bx, acc[mt], 0, 0, 0); \
  } while (0)

  STAGE_RT(&lds3[0][0], 0);
  STAGE_RT(&lds3[1][0], 256);
  waitbar3();
  int cur = 0;
#pragma unroll 3
  for (int t = 0; t < 6; ++t) {
    int nx = cur + 2; if (nx >= 3) nx -= 3;
    STAGE_RT(&lds3[nx][0], (t + 2) * 256);
    COMPUTE_RT(&lds3[cur][0]);
    waitbar3();
    ++cur; if (cur == 3) cur = 0;
  }
  COMPUTE_RT(&lds3[cur][0]);  // t=6
  waitbar0();
  ++cur; if (cur == 3) cur = 0;
  COMPUTE_RT(&lds3[cur][0]);  // t=7
  __syncthreads();

  // cross-wave reduction of the 8 K-slices
  float* red = (float*)&lds3[0][0];  // 16 KB
  int li = (wave * 64 + lane) * 8;
#pragma unroll
  for (int mt = 0; mt < 2; mt++)
#pragma unroll
    for (int r = 0; r < 4; r++) red[li + mt * 4 + r] = acc[mt][r];
  __syncthreads();
  if (wave == 0) {
    float lg[2][4];
    float m = -1e30f;
#pragma unroll
    for (int mt = 0; mt < 2; mt++)
#pragma unroll
      for (int r = 0; r < 4; r++) {
        float v = 0.f;
#pragma unroll
        for (int w = 0; w < 8; w++) v += red[(w * 64 + lane) * 8 + mt * 4 + r];
        int wc = mt * 16 + lq * 4 + r;
        v += (wc < 26) ? br[wc] : -1e30f;
        lg[mt][r] = v;
        m = fmaxf(m, v);
      }
    m = fmaxf(m, __shfl_xor(m, 16));
    m = fmaxf(m, __shfl_xor(m, 32));
    float s = 0.f;
#pragma unroll
    for (int mt = 0; mt < 2; mt++)
#pragma unroll
      for (int r = 0; r < 4; r++) s += expf(lg[mt][r] - m);
    s += __shfl_xor(s, 16);
    s += __shfl_xor(s, 32);
    float ls = logf(s);
    int b = r0 + lr;
    int lab = labels[b];
    int j = lab / 40;
    float pen = 0.f;
#pragma unroll
    for (int mt = 0; mt < 2; mt++)
#pragma unroll
      for (int r = 0; r < 4; r++) {
        int wc = mt * 16 + lq * 4 + r;
        float lp = lg[mt][r] - m - ls;
        if (wc < 26) rootp[(size_t)b * 32 + wc] = expf(lp);
        if (wc == j + 1) pen -= lp;
      }
    for (int off = 32; off; off >>= 1) pen += __shfl_down(pen, off);
    if (lane == 0) atomicAdd(pengl, pen * (1.f / 4096.f));
  }
}

// ---------------- kernel: lvl2 grouped GEMM, M=128 x N=192 (4 groups), 8 waves,
// ring-3 LDS, counted vmcnt(5) ----------------
__global__ __launch_bounds__(512) void k_lvl2(const unsigned short* __restrict__ xbf,
                                              const unsigned short* __restrict__ wlt,
                                              const float* __restrict__ bl,
                                              const int* __restrict__ labels,
                                              const float* __restrict__ rootp,
                                              float* __restrict__ out,
                                              float* __restrict__ pengl) {
  __shared__ __align__(16) unsigned char lds3[3][40960];  // x 16K @0, w 24K @16384
  int bid = blockIdx.x;                      // 224 = 32 row-tiles * 7 group-quads
  int swz = (bid & 7) * 28 + (bid >> 3);     // XCD-chunked, bijective (224 = 8*28)
  int rt = swz / 7, quad = swz % 7;
  int r0 = rt * 128, n0 = quad * 4;
  int tid = threadIdx.x, lane = tid & 63, wave = tid >> 6;  // 8 waves
  int wr = wave >> 2, wcq = wave & 3;        // 2x4 wave grid: rows wr*64, group n0+wcq
  int lq = lane >> 4, lr = lane & 15;
  f32x4 acc[3][4] = {};
  const unsigned short* xg = xbf + (size_t)r0 * 2048;
  const unsigned short* wg = wlt + (size_t)n0 * 48 * 2048;  // 192 contiguous rows

  // 5 gload_lds per thread per stage, uniform across waves
#define STAGE_L2(lb, kk)                                                              \
  do {                                                                                \
    _Pragma("unroll")                                                                 \
    for (int i = 0; i < 2; i++) { /* x: 1024 chunks */                                \
      int idx = i * 512 + tid;                                                        \
      int row = idx >> 3, s = idx & 7;                                                \
      const unsigned short* gp = xg + (size_t)row * 2048 + (kk) + ((s ^ (row & 7)) << 3); \
      GLOAD16(gp, (lb) + (size_t)idx * 16);                                           \
    }                                                                                 \
    _Pragma("unroll")                                                                 \
    for (int i = 0; i < 3; i++) { /* w: 1536 chunks (192 rows) */                     \
      int idx = i * 512 + tid;                                                        \
      int wc = idx >> 3, s = idx & 7;                                                 \
      const unsigned short* gp = wg + (size_t)wc * 2048 + (kk) + ((s ^ (wc & 7)) << 3); \
      GLOAD16(gp, (lb) + 16384 + (size_t)idx * 16);                                   \
    }                                                                                 \
  } while (0)

#define COMPUTE_L2(base)                                                              \
  do {                                                                                \
    _Pragma("unroll")                                                                 \
    for (int ks = 0; ks < 2; ks++) {                                                  \
      int g = (ks << 2) | lq;                                                         \
      bf16x8 af[3], bx[4];                                                            \
      _Pragma("unroll")                                                               \
      for (int mt = 0; mt < 3; mt++) {                                                \
        int c = wcq * 48 + mt * 16 + lr;                                              \
        af[mt] = *reinterpret_cast<const bf16x8*>((base) + 16384 + c * 128 + ((g ^ (c & 7)) << 4)); \
      }                                                                               \
      _Pragma("unroll")                                                               \
      for (int nt = 0; nt < 4; nt++) {                                                \
        int row = wr * 64 + nt * 16 + lr;                                             \
        bx[nt] = *reinterpret_cast<const bf16x8*>((base) + row * 128 + ((g ^ (row & 7)) << 4)); \
      }                                                                               \
      _Pragma("unroll")                                                               \
      for (int mt = 0; mt < 3; mt++)                                                  \
        _Pragma("unroll")                                                             \
        for (int nt = 0; nt < 4; nt++)                                                \
          acc[mt][nt] = __builtin_amdgcn_mfma_f32_16x16x32_bf16(af[mt], bx[nt], acc[mt][nt], 0, 0, 0); \
    }                                                                                 \
  } while (0)

  STAGE_L2(&lds3[0][0], 0);
  STAGE_L2(&lds3[1][0], 64);
  waitbar5();
  int cur = 0;
#pragma unroll 3
  for (int t = 0; t < 30; ++t) {
    int nx = cur + 2; if (nx >= 3) nx -= 3;
    STAGE_L2(&lds3[nx][0], (t + 2) * 64);
    COMPUTE_L2(&lds3[cur][0]);
    waitbar5();
    ++cur; if (cur == 3) cur = 0;
  }
  COMPUTE_L2(&lds3[cur][0]);  // t=30 (buf 0)
  waitbar0();
  ++cur; if (cur == 3) cur = 0;
  COMPUTE_L2(&lds3[cur][0]);  // t=31 (buf 1)

  // epilogue: per-wave group n = n0 + wcq; softmax per row within the wave
  int n = n0 + wcq;
  bool valid = (n < 25);
  float bb[3][4];
#pragma unroll
  for (int mt = 0; mt < 3; mt++)
#pragma unroll
    for (int r = 0; r < 4; r++) {
      int wcg = mt * 16 + lq * 4 + r;
      bb[mt][r] = (valid && wcg < 41) ? bl[n * 41 + wcg] : -1e30f;
    }
  float pen = 0.f;
#pragma unroll
  for (int nt = 0; nt < 4; nt++) {
    int b = r0 + wr * 64 + nt * 16 + lr;
    float lg[3][4];
    float m = -1e30f;
#pragma unroll
    for (int mt = 0; mt < 3; mt++)
#pragma unroll
      for (int r = 0; r < 4; r++) {
        float v = acc[mt][nt][r] + bb[mt][r];
        lg[mt][r] = v;
        m = fmaxf(m, v);
      }
    m = fmaxf(m, __shfl_xor(m, 16));
    m = fmaxf(m, __shfl_xor(m, 32));
    float s = 0.f;
#pragma unroll
    for (int mt = 0; mt < 3; mt++)
#pragma unroll
      for (int r = 0; r < 4; r++) s += expf(lg[mt][r] - m);
    s += __shfl_xor(s, 16);
    s += __shfl_xor(s, 32);
    float ls = logf(s);
    float rp = valid ? rootp[(size_t)b * 32 + (n + 1)] : 0.f;
    int lab = labels[b];
    int j = lab / 40;
    int sub = (j == n) ? (lab - j * 40 + 1) : 0;
#pragma unroll
    for (int mt = 0; mt < 3; mt++)
#pragma unroll
      for (int r = 0; r < 4; r++) {
        int wcg = mt * 16 + lq * 4 + r;
        float lp = lg[mt][r] - m - ls;
        if (valid && wcg >= 1 && wcg < 41) out[(size_t)b * 1000 + n * 40 + wcg - 1] = expf(lp) * rp;
        if (valid && wcg == sub) pen -= lp;
      }
  }
  for (int off = 32; off; off >>= 1) pen += __shfl_down(pen, off);
  float* red = (float*)&lds3[0][0];  // buf0 idle: t=31 computed buf1
  if (lane == 0) red[wave] = pen;
  __syncthreads();
  if (tid == 0) {
    float tot = 0.f;
#pragma unroll
    for (int w = 0; w < 8; w++) tot += red[w];
    atomicAdd(pengl, tot * (1.f / 8192.f));
  }
}

extern "C" void kernel_launch(void* const* d_in, const int* in_sizes, int n_in,
                              void* d_out, int out_size, void* d_ws, size_t ws_size,
                              hipStream_t stream) {
  const float* x = (const float*)d_in[0];
  const int* labels_raw = (const int*)d_in[1];
  const float* wroot = (const float*)d_in[2];
  const float* broot = (const float*)d_in[3];
  const float* wlvl2 = (const float*)d_in[4];
  const float* blvl2 = (const float*)d_in[5];
  float* out = (float*)d_out;
  float* pengl = out + 4096000;

  char* ws = (char*)d_ws;
  unsigned short* xbf = (unsigned short*)ws;                    // 16,777,216 B
  unsigned short* wlt = (unsigned short*)(ws + 16777216);       //  5,505,024 B (28x48x2048)
  unsigned short* wrt = (unsigned short*)(ws + 22282240);       //    131,072 B (32x2048)
  float* rootp = (float*)(ws + 22413312);                       //    524,288 B
  int* lab32 = (int*)(ws + 22937600);                           //     16,384 B

  k_prep<<<4932, TB, 0, stream>>>(x, wlvl2, wroot, labels_raw, xbf, wlt, wrt, lab32, pengl);
  k_root<<<256, 512, 0, stream>>>(xbf, wrt, broot, lab32, rootp, pengl);
  k_lvl2<<<224, 512, 0, stream>>>(xbf, wlt, blvl2, lab32, rootp, out, pengl);
}